// Round 11
// baseline (778.640 us; speedup 1.0000x reference)
//
#include <hip/hip_runtime.h>
#include <hip/hip_bf16.h>

#define N_NODES 50000
#define E_EDGES 800000
#define IN_F 128
#define H_HEADS 8
#define C_CH 32
#define HC 256                   // H*C
#define G_GRAPHS 64
#define NEG_SLOPE 0.2f
#define NCHUNK 49                // ceil(N/1024)

__device__ __forceinline__ unsigned short f2bf(float f) {   // RNE float->bf16
    unsigned u = __float_as_uint(f);
    u += 0x7fffu + ((u >> 16) & 1u);
    return (unsigned short)(u >> 16);
}

// h_bf = bf16(x@W) [N,256]; a_src/a_dst = per-(node,head) fp32 logits.
// 8 nodes per block; 256 threads = one output column each.
__global__ __launch_bounds__(256) void k_gemm(const float* __restrict__ x,
        const float* __restrict__ W, const float* __restrict__ att_src,
        const float* __restrict__ att_dst, unsigned short* __restrict__ hb,
        float* __restrict__ a_src, float* __restrict__ a_dst) {
    __shared__ float xs[8 * IN_F];
    const int n0 = blockIdx.x * 8;
    const int tid = threadIdx.x;
    ((float4*)xs)[tid] = ((const float4*)(x + (size_t)n0 * IN_F))[tid];
    __syncthreads();

    const int j = tid;            // output column 0..255
    float acc[8];
    #pragma unroll
    for (int r = 0; r < 8; ++r) acc[r] = 0.f;

    const float4* xs4 = (const float4*)xs;
    for (int k4 = 0; k4 < IN_F / 4; ++k4) {
        const float w0 = W[(k4 * 4 + 0) * HC + j];
        const float w1 = W[(k4 * 4 + 1) * HC + j];
        const float w2 = W[(k4 * 4 + 2) * HC + j];
        const float w3 = W[(k4 * 4 + 3) * HC + j];
        #pragma unroll
        for (int r = 0; r < 8; ++r) {
            float4 xv = xs4[r * (IN_F / 4) + k4];
            acc[r] += xv.x * w0 + xv.y * w1 + xv.z * w2 + xv.w * w3;
        }
    }

    const float asv = att_src[j], adv = att_dst[j];
    const int hh = j >> 5;
    #pragma unroll
    for (int r = 0; r < 8; ++r) {
        hb[(size_t)(n0 + r) * HC + j] = f2bf(acc[r]);
        float s = acc[r] * asv, d = acc[r] * adv;
        #pragma unroll
        for (int off = 16; off; off >>= 1) {   // reduce within each 32-lane head group
            s += __shfl_xor(s, off, 64);
            d += __shfl_xor(d, off, 64);
        }
        if ((tid & 31) == 0) {
            a_src[(n0 + r) * H_HEADS + hh] = s;
            a_dst[(n0 + r) * H_HEADS + hh] = d;
        }
    }
}

// in-degree histogram (real edges only; self-loops handled in k_node)
__global__ __launch_bounds__(256) void k_hist(const int* __restrict__ ei,
        int* __restrict__ deg) {
    int i = blockIdx.x * 256 + threadIdx.x;
    if (i < E_EDGES) atomicAdd(deg + ei[E_EDGES + i], 1);
}

// per-1024-node chunk sums of deg — contention-free reduction, 49 blocks
__global__ __launch_bounds__(256) void k_chunksum(const int* __restrict__ deg,
        int* __restrict__ chunk) {
    __shared__ int ws4[4];
    const int tid = threadIdx.x, lane = tid & 63, wid = tid >> 6;
    const int base = blockIdx.x * 1024 + tid * 4;
    int s = 0;
    #pragma unroll
    for (int u = 0; u < 4; ++u) {
        int i = base + u;
        if (i < N_NODES) s += deg[i];
    }
    #pragma unroll
    for (int o = 32; o; o >>= 1) s += __shfl_xor(s, o, 64);
    if (lane == 0) ws4[wid] = s;
    __syncthreads();
    if (tid == 0) chunk[blockIdx.x] = ws4[0] + ws4[1] + ws4[2] + ws4[3];
}

// exclusive scan of the 49 chunk sums (one wave)
__global__ __launch_bounds__(64) void k_chunkscan(const int* __restrict__ chunk,
        int* __restrict__ chunkoff) {
    int t = threadIdx.x;
    int v = (t < NCHUNK) ? chunk[t] : 0;
    int s = v;
    #pragma unroll
    for (int d = 1; d < 64; d <<= 1) {
        int u = __shfl_up(s, d, 64);
        if (t >= d) s += u;
    }
    if (t < NCHUNK) chunkoff[t] = s - v;
}

// per-chunk local scan (+ chunk base) -> off, cursor
__global__ __launch_bounds__(1024) void k_localscan(const int* __restrict__ deg,
        const int* __restrict__ chunkoff, int* __restrict__ off,
        int* __restrict__ cursor) {
    __shared__ int wsum[16];
    const int tid = threadIdx.x, lane = tid & 63, wid = tid >> 6;
    const int i = blockIdx.x * 1024 + tid;
    int v = (i < N_NODES) ? deg[i] : 0;
    int s = v;
    #pragma unroll
    for (int d = 1; d < 64; d <<= 1) {
        int t = __shfl_up(s, d, 64);
        if (lane >= d) s += t;
    }
    if (lane == 63) wsum[wid] = s;
    __syncthreads();
    if (wid == 0 && lane < 16) {
        int t = wsum[lane];
        #pragma unroll
        for (int d = 1; d < 16; d <<= 1) {
            int u = __shfl_up(t, d, 64);
            if (lane >= d) t += u;
        }
        wsum[lane] = t;
    }
    __syncthreads();
    int wpre = wid ? wsum[wid - 1] : 0;
    if (i < N_NODES) {
        int excl = chunkoff[blockIdx.x] + wpre + s - v;
        off[i] = excl;
        cursor[i] = excl;
    }
    if (blockIdx.x == NCHUNK - 1 && tid == 0) off[N_NODES] = E_EDGES;
}

// scatter src indices into CSR-by-dst
__global__ __launch_bounds__(256) void k_scatter(const int* __restrict__ ei,
        int* __restrict__ cursor, int* __restrict__ csr_src) {
    int i = blockIdx.x * 256 + threadIdx.x;
    if (i >= E_EDGES) return;
    int dst = ei[E_EDGES + i];
    int p = atomicAdd(cursor + dst, 1);
    csr_src[p] = ei[i];
}

// acc[j] += w * bf16(channel 8*l32+j) for a 16B (8-channel) chunk
__device__ __forceinline__ void accum8w(float* acc, uint4 q, float w) {
    acc[0] += w * __uint_as_float(q.x << 16);
    acc[1] += w * __uint_as_float(q.x & 0xffff0000u);
    acc[2] += w * __uint_as_float(q.y << 16);
    acc[3] += w * __uint_as_float(q.y & 0xffff0000u);
    acc[4] += w * __uint_as_float(q.z << 16);
    acc[5] += w * __uint_as_float(q.z & 0xffff0000u);
    acc[6] += w * __uint_as_float(q.w << 16);
    acc[7] += w * __uint_as_float(q.w & 0xffff0000u);
}

// One 64-lane wave per destination node, TWO edges per gather instruction:
// lanes 0-31 handle edge 2u, lanes 32-63 edge 2u+1. Lane covers 8 channels
// (uint4 of bf16), head hh = (lane&31)>>2. Explicit 2-deep software pipeline
// (two named register batches of 8 edges / 4 packed gathers each) keeps a
// full batch of gathers in flight while the previous is consumed.
__global__ __launch_bounds__(256) void k_node(const unsigned short* __restrict__ hb,
        const float* __restrict__ a_src, const float* __restrict__ a_dst,
        const int* __restrict__ off, const int* __restrict__ csr_src,
        const int* __restrict__ batch, const float* __restrict__ bias,
        float* __restrict__ pool, float* __restrict__ cnt) {
    const int wave = threadIdx.x >> 6, lane = threadIdx.x & 63;
    const int n = blockIdx.x * 4 + wave;
    if (n >= N_NODES) return;
    const int half = lane >> 5;          // which edge of the pair
    const int l32 = lane & 31;
    const int hh = l32 >> 2;             // head: 4 lanes per head per half
    const int beg = off[n], end = off[n + 1];
    const float adst = a_dst[n * H_HEADS + hh];

    float acc[8] = {0.f, 0.f, 0.f, 0.f, 0.f, 0.f, 0.f, 0.f};
    float denom = 0.f;

    {   // self-loop: both halves load the same row; upper half weight 0
        float e = a_src[n * H_HEADS + hh] + adst;
        e = e > 0.f ? e : NEG_SLOPE * e;
        float w = half ? 0.f : __expf(e);
        uint4 q = ((const uint4*)(hb + (size_t)n * HC))[l32];
        denom += w;
        accum8w(acc, q, w);
    }

    auto issue = [&](int kk, uint4* q, float* ea) {
        #pragma unroll
        for (int u = 0; u < 4; ++u) {
            int s0 = csr_src[kk + 2 * u];        // wave-uniform -> scalar loads
            int s1 = csr_src[kk + 2 * u + 1];
            int s = half ? s1 : s0;
            q[u] = ((const uint4*)(hb + (size_t)s * HC))[l32];
            ea[u] = a_src[s * H_HEADS + hh];
        }
    };
    auto consume = [&](const uint4* q, const float* ea) {
        #pragma unroll
        for (int u = 0; u < 4; ++u) {
            float e = ea[u] + adst;
            e = e > 0.f ? e : NEG_SLOPE * e;
            float w = __expf(e);
            denom += w;
            accum8w(acc, q[u], w);
        }
    };

    const int nfull = (end - beg) & ~7;  // edges handled in 8-edge batches
    const int nb = nfull >> 3;
    uint4 qA[4], qB[4];
    float eA[4], eB[4];
    if (nb > 0) {
        issue(beg, qA, eA);
        for (int b = 1; b < nb; ++b) {
            if (b & 1) { issue(beg + 8 * b, qB, eB); consume(qA, eA); }
            else       { issue(beg + 8 * b, qA, eA); consume(qB, eB); }
        }
        if (nb & 1) consume(qA, eA); else consume(qB, eB);
    }

    // remainder: pairs, then possible single edge
    int k = beg + nfull;
    for (; k + 1 < end; k += 2) {
        int s0 = csr_src[k], s1 = csr_src[k + 1];
        int s = half ? s1 : s0;
        uint4 q = ((const uint4*)(hb + (size_t)s * HC))[l32];
        float e = a_src[s * H_HEADS + hh] + adst;
        e = e > 0.f ? e : NEG_SLOPE * e;
        float w = __expf(e);
        denom += w;
        accum8w(acc, q, w);
    }
    if (k < end) {
        int s = csr_src[k];
        uint4 q = ((const uint4*)(hb + (size_t)s * HC))[l32];
        float e = a_src[s * H_HEADS + hh] + adst;
        e = e > 0.f ? e : NEG_SLOPE * e;
        float w = half ? 0.f : __expf(e);
        denom += w;
        accum8w(acc, q, w);
    }

    // combine the two halves (disjoint edge subsets of the same node)
    #pragma unroll
    for (int j = 0; j < 8; ++j) acc[j] += __shfl_xor(acc[j], 32, 64);
    denom += __shfl_xor(denom, 32, 64);

    const float inv = 0.125f / (denom + 1e-16f);   // alpha-norm + head-mean /8
    float r[8];
    #pragma unroll
    for (int j = 0; j < 8; ++j) r[j] = acc[j] * inv;
    // sum across the 8 heads: lanes differing in bits 2..4
    #pragma unroll
    for (int o = 4; o <= 16; o <<= 1) {
        #pragma unroll
        for (int j = 0; j < 8; ++j) r[j] += __shfl_xor(r[j], o, 64);
    }
    if (lane < 4) {
        const int g = batch[n];
        const int c0 = lane * 8;
        float* pg = pool + g * C_CH + c0;
        #pragma unroll
        for (int j = 0; j < 8; ++j) {
            float o = r[j] + bias[c0 + j];
            o = o > 0.f ? o : 0.f;                 // relu
            atomicAdd(pg + j, o);
        }
        if (lane == 0) atomicAdd(cnt + g, 1.f);
    }
}

// Final: pooled mean + [G,2] linear; writes x_t then pooled into d_out.
__global__ __launch_bounds__(256) void k_final(const float* __restrict__ pool,
        const float* __restrict__ cnt, const float* __restrict__ lin_w,
        const float* __restrict__ lin_b, float* __restrict__ out) {
    __shared__ float pd[G_GRAPHS * C_CH];
    int t = threadIdx.x;
    for (int i = t; i < G_GRAPHS * C_CH; i += 256) {
        int g = i >> 5;
        float p = pool[i] / fmaxf(cnt[g], 1.f);
        pd[i] = p;
        out[G_GRAPHS * 2 + i] = p;              // pooled output (tuple elem 2)
    }
    __syncthreads();
    if (t < G_GRAPHS * 2) {
        int g = t >> 1, o = t & 1;
        float s = lin_b[o];
        #pragma unroll
        for (int c = 0; c < C_CH; ++c) s += pd[g * C_CH + c] * lin_w[c * 2 + o];
        out[t] = s;                             // x_t output (tuple elem 1)
    }
}

extern "C" void kernel_launch(void* const* d_in, const int* in_sizes, int n_in,
                              void* d_out, int out_size, void* d_ws, size_t ws_size,
                              hipStream_t stream) {
    const float* x       = (const float*)d_in[0];
    const int*   ei      = (const int*)d_in[1];
    const int*   batch   = (const int*)d_in[2];
    const float* W       = (const float*)d_in[3];
    const float* att_src = (const float*)d_in[4];
    const float* att_dst = (const float*)d_in[5];
    const float* bias    = (const float*)d_in[6];
    const float* lin_w   = (const float*)d_in[7];
    const float* lin_b   = (const float*)d_in[8];

    char* ws = (char*)d_ws;
    unsigned short* hb   = (unsigned short*)(ws);   // 25,600,000
    float* a_src   = (float*)(ws + 25600000);       //  1,600,000
    float* a_dst   = (float*)(ws + 27200000);       //  1,600,000
    int*   deg     = (int*)  (ws + 28800000);       //    200,000
    int*   chunk   = (int*)  (ws + 29000000);       //        256
    int*   off     = (int*)  (ws + 29000256);       //    200,064
    int*   cursor  = (int*)  (ws + 29200512);       //    200,000
    int*   csr_src = (int*)  (ws + 29400512);       //  3,200,000
    float* pool    = (float*)(ws + 32600512);       //      8,192
    float* cnt     = (float*)(ws + 32608704);       //        256
    int*   chunkoff= (int*)  (ws + 32608960);       //        256
    // total ~32.6 MB

    hipMemsetAsync(deg, 0, 200000, stream);
    hipMemsetAsync(pool, 0, 8192 + 256, stream);    // pool + cnt contiguous

    k_gemm<<<N_NODES / 8, 256, 0, stream>>>(x, W, att_src, att_dst, hb, a_src, a_dst);
    k_hist<<<(E_EDGES + 255) / 256, 256, 0, stream>>>(ei, deg);
    k_chunksum<<<NCHUNK, 256, 0, stream>>>(deg, chunk);
    k_chunkscan<<<1, 64, 0, stream>>>(chunk, chunkoff);
    k_localscan<<<NCHUNK, 1024, 0, stream>>>(deg, chunkoff, off, cursor);
    k_scatter<<<(E_EDGES + 255) / 256, 256, 0, stream>>>(ei, cursor, csr_src);
    k_node<<<(N_NODES + 3) / 4, 256, 0, stream>>>(
        hb, a_src, a_dst, off, csr_src, batch, bias, pool, cnt);
    k_final<<<1, 256, 0, stream>>>(pool, cnt, lin_w, lin_b, (float*)d_out);
}